// Round 19
// baseline (1118.070 us; speedup 1.0000x reference)
//
#include <hip/hip_runtime.h>
#include <hip/hip_bf16.h>

#define B_ 8
#define N_ 4096
#define K_ 16
#define D_ 128

typedef short bf16x8 __attribute__((ext_vector_type(8)));
typedef float f32x4 __attribute__((ext_vector_type(4)));

__device__ __forceinline__ short bfr(float x){
  __hip_bfloat16 h = __float2bfloat16(x);
  return *reinterpret_cast<short*>(&h);
}

// ---------------- prep: weights in MFMA-FRAGMENT ORDER + zero stats ---------
__global__ __launch_bounds__(256) void prep_kernel(
    const float* __restrict__ W1, const float* __restrict__ Wf, const float* __restrict__ cw2,
    short* __restrict__ W1Tf, short* __restrict__ WfTf, short* __restrict__ cw2f,
    float* __restrict__ stats)
{
  int t = blockIdx.x*256 + threadIdx.x;
  if (t < 16384) {                       // W1 frags: t(8) x ks(4) x lane x j
    int u = t;
    int j = u & 7, L = (u >> 3) & 63, ks = (u >> 9) & 3, tt = u >> 11;
    int d = tt*16 + (L & 15);
    int c = ks*32 + (L >> 4)*8 + j;
    W1Tf[u] = bfr(W1[c*128 + d]);        // W1 is [CIN=128][D=128]
  } else if (t < 49152) {                // Wf frags: t(8) x ks(8) x lane x j
    int u = t - 16384;
    int j = u & 7, L = (u >> 3) & 63, ks = (u >> 9) & 7, tt = u >> 12;
    int d = tt*16 + (L & 15);
    int c = ks*32 + (L >> 4)*8 + j;
    WfTf[u] = bfr(Wf[c*128 + d]);        // Wf is [2D=256][D=128]
  } else if (t < 57344) {                // cw2 frags: t(8) x ks(2) x lane x j
    int u = t - 49152;
    int j = u & 7, L = (u >> 3) & 63, ks = (u >> 9) & 1, tt = u >> 10;
    int d = tt*16 + (L & 15);
    int c = ks*32 + (L >> 4)*8 + j;
    cw2f[u] = bfr(cw2[d*64 + c]);        // cw2 is [D=128][D/2=64]
  } else if (t < 57360) {
    stats[t - 57344] = 0.0f;
  }
}

// ---------------- knn: quarter scan (1024 cands, 16KB LDS) ------------------
// Scan/merge body byte-identical to green R18; only geometry changed
// (quarters instead of halves) to lift block residency per CU.
__device__ __forceinline__ void insert16(float (&bd)[16], int (&bi)[16], float d, int cid){
  #pragma unroll
  for (int j = 15; j >= 1; --j){
    bool ltj = d < bd[j];
    bool ltp = d < bd[j-1];
    float nd = ltj ? (ltp ? bd[j-1] : d) : bd[j];
    int   ni = ltj ? (ltp ? bi[j-1] : cid) : bi[j];
    bd[j] = nd; bi[j] = ni;
  }
  bool lt0 = d < bd[0];
  bd[0] = lt0 ? d : bd[0];
  bi[0] = lt0 ? cid : bi[0];
}

__device__ __forceinline__ void insert16t(float (&bd)[16], int (&bi)[16], float d, int cid){
  bool lt[16];
  #pragma unroll
  for (int j = 0; j < 16; ++j)
    lt[j] = (d < bd[j]) || ((d == bd[j]) && (cid < bi[j]));
  #pragma unroll
  for (int j = 15; j >= 1; --j){
    float nd = lt[j] ? (lt[j-1] ? bd[j-1] : d) : bd[j];
    int   ni = lt[j] ? (lt[j-1] ? bi[j-1] : cid) : bi[j];
    bd[j] = nd; bi[j] = ni;
  }
  if (lt[0]){ bd[0] = d; bi[0] = cid; }
}

// grid = 2048 blocks: b = blk>>8, qtr = (blk>>6)&3, qblk = (blk&63)<<6.
// 512 threads = 8 waves; 8 queries/wave (q=lane&7), 8 slices of 128 (s=lane>>3).
__global__ __launch_bounds__(512) void knn_split_kernel(
    const float* __restrict__ xyz,
    float* __restrict__ pdb, int* __restrict__ pib)
{
  __shared__ float4 cand[1024];          // 16 KB: x,y,z,|p|^2 (XOR-swizzled)
  int b    = blockIdx.x >> 8;            // batch
  int qtr  = (blockIdx.x >> 6) & 3;      // candidate quarter
  int qblk = (blockIdx.x & 63) << 6;     // 64 queries per block
  int hbase = qtr << 10;                 // 1024*qtr
  const float* xb = xyz + b*N_*3;
  for (int i = threadIdx.x; i < 1024; i += 512){
    int gi = hbase + i;
    float x = xb[gi*3+0], y = xb[gi*3+1], z = xb[gi*3+2];
    int e = i ^ ((i >> 7) & 7);          // swizzled slot (bijection within slice)
    cand[e] = make_float4(x, y, z, x*x + y*y + z*z);
  }
  __syncthreads();

  int wv = threadIdx.x >> 6, lane = threadIdx.x & 63;
  int q = lane & 7;                      // query within wave's 8
  int s = lane >> 3;                     // slice 0..7 (128 cands each)
  int qi = qblk + (wv << 3) + q;         // batch-local query index
  const float* qp = xb + qi*3;
  float qx = qp[0], qy = qp[1], qz = qp[2];
  float4 qc = make_float4(qx, qy, qz, qx*qx + qy*qy + qz*qz);

  float bd[16]; int bi[16];
  #pragma unroll
  for (int j = 0; j < 16; ++j){ bd[j] = 3.4e38f; bi[j] = 0x7fffffff; }

  // ascending-index scan of slice [s*128, (s+1)*128) — simple body
  int cbase = s << 7;
  for (int m = 0; m < 128; ++m){
    float4 c = cand[cbase + (m ^ s)];
    float t = qc.x*c.x + qc.y*c.y + qc.z*c.z;
    float d = (qc.w + c.w) - 2.0f*t;
    if (d < bd[15]) insert16(bd, bi, d, cbase + m);
  }

  // lex-aware absorb-tree merge over slice bits (order-independent)
  #pragma unroll
  for (int xm = 32; xm >= 8; xm >>= 1){
    bool absorb = (lane & xm) == 0;
    #pragma unroll
    for (int j = 0; j < 16; ++j){
      float pdj = __shfl_xor(bd[j], xm);
      int   pij = __shfl_xor(bi[j], xm);
      if (absorb) insert16t(bd, bi, pdj, pij);
    }
  }

  // lanes with s==0 write this quarter's exact lex-sorted partial list
  if (s == 0){
    int gq = b*N_ + qi;
    float* pdh = pdb + qtr*524288;       // 32768*16 per quarter
    int*   pih = pib + qtr*524288;
    #pragma unroll
    for (int j = 0; j < 16; ++j){
      pdh[gq*16 + j] = bd[j];
      pih[gq*16 + j] = bi[j] + hbase;    // translate to global candidate index
    }
  }
}

// lex compare on stored scan bits (no recompute -> no drift)
__device__ __forceinline__ bool lexlt(float da, int ia, float db, int ib){
  return (da < db) || ((da == db) && (ia < ib));
}

// ad/ai (asc) + bdv/biv (asc) -> ad/ai = lowest 16 of union, ascending
// (R15-proven stage+clean bitonic pattern, static indices)
__device__ __forceinline__ void low16(float (&ad)[16], int (&ai)[16],
                                      const float (&bdv)[16], const int (&biv)[16]){
  float md[16]; int mi[16];
  #pragma unroll
  for (int i = 0; i < 16; ++i){
    bool t = lexlt(ad[i], ai[i], bdv[15-i], biv[15-i]);
    md[i] = t ? ad[i] : bdv[15-i];
    mi[i] = t ? ai[i] : biv[15-i];
  }
  #pragma unroll
  for (int j = 8; j > 0; j >>= 1){
    #pragma unroll
    for (int i = 0; i < 16; ++i){
      int l = i ^ j;
      if (l > i){
        bool t = lexlt(md[l], mi[l], md[i], mi[i]);   // true -> swap
        float lo_d = t ? md[l] : md[i]; int lo_i = t ? mi[l] : mi[i];
        float hi_d = t ? md[i] : md[l]; int hi_i = t ? mi[i] : mi[l];
        md[i] = lo_d; mi[i] = lo_i; md[l] = hi_d; mi[l] = hi_i;
      }
    }
  }
  #pragma unroll
  for (int i = 0; i < 16; ++i){ ad[i] = md[i]; ai[i] = mi[i]; }
}

__global__ __launch_bounds__(512) void knn_merge_kernel(
    const float* __restrict__ xyz,
    const float* __restrict__ pdb, const int* __restrict__ pib,
    int* __restrict__ idx_out, float* __restrict__ stats)
{
  int gq = blockIdx.x*512 + threadIdx.x;   // 64 blocks x 512 = 32768 queries
  int b = gq >> 12, qi = gq & 4095;

  float ad[16]; int ai[16];
  #pragma unroll
  for (int j = 0; j < 16; ++j){
    ad[j] = pdb[gq*16 + j];
    ai[j] = pib[gq*16 + j];
  }
  #pragma unroll
  for (int qtr = 1; qtr < 4; ++qtr){
    float ld[16]; int li[16];
    #pragma unroll
    for (int j = 0; j < 16; ++j){
      ld[j] = pdb[qtr*524288 + gq*16 + j];
      li[j] = pib[qtr*524288 + gq*16 + j];
    }
    low16(ad, ai, ld, li);
  }

  const float* qp = xyz + (b*N_ + qi)*3;
  float qx = qp[0], qy = qp[1], qz = qp[2];
  float sv[9];
  #pragma unroll
  for (int i = 0; i < 9; ++i) sv[i] = 0.0f;
  #pragma unroll
  for (int j = 0; j < 16; ++j){
    idx_out[gq*16 + j] = ai[j];
    const float* np = xyz + (b*N_ + ai[j])*3;
    float rx = np[0]-qx, ry = np[1]-qy, rz = np[2]-qz;
    sv[0] += rx;    sv[1] += ry;    sv[2] += rz;
    sv[3] += rx*rx; sv[4] += ry*ry; sv[5] += rz*rz;
    sv[6] += rx*ry; sv[7] += rx*rz; sv[8] += ry*rz;
  }
  #pragma unroll
  for (int i = 0; i < 9; ++i){
    float v = sv[i];
    #pragma unroll
    for (int mask = 1; mask < 64; mask <<= 1) v += __shfl_xor(v, mask);
    if ((threadIdx.x & 63) == 0) atomicAdd(&stats[i], v);
  }
}

// ---------------- BN finalize ----------------
__global__ void bn_finalize_kernel(
    const float* __restrict__ stats, const float* __restrict__ cw1, const float* __restrict__ cb1,
    const float* __restrict__ bn_g, const float* __restrict__ bn_b,
    float* __restrict__ bnsc, float* __restrict__ bnsh)
{
  int o = threadIdx.x;
  if (o >= 64) return;
  const float inv = 1.0f / (float)(B_*N_*K_);
  float m1x = stats[0]*inv, m1y = stats[1]*inv, m1z = stats[2]*inv;
  float mxx = stats[3]*inv, myy = stats[4]*inv, mzz = stats[5]*inv;
  float mxy = stats[6]*inv, mxz = stats[7]*inv, myz = stats[8]*inv;
  float w0 = cw1[o*3], w1 = cw1[o*3+1], w2 = cw1[o*3+2], cb = cb1[o];
  float wm = w0*m1x + w1*m1y + w2*m1z;
  float mu = wm + cb;
  float e2 = w0*w0*mxx + w1*w1*myy + w2*w2*mzz
           + 2.0f*(w0*w1*mxy + w0*w2*mxz + w1*w2*myz)
           + 2.0f*cb*wm + cb*cb;
  float var = e2 - mu*mu;
  float sc = bn_g[o] * rsqrtf(var + 1e-5f);
  bnsc[o] = sc;
  bnsh[o] = bn_b[o] - mu*sc;
}

// ---------------- main fused kernel: 1 wave = 1 point, low-VGPR -------------
__device__ __forceinline__ void ln_silu_store(
    f32x4 (&acc)[8], const float (&pb)[8], const float (&pg)[8], const float (&pe)[8],
    short* fw, int g, int c16)
{
  float sm[4] = {0,0,0,0}, sq[4] = {0,0,0,0};
  #pragma unroll
  for (int t = 0; t < 8; ++t){
    #pragma unroll
    for (int r = 0; r < 4; ++r){
      float v = acc[t][r] + pb[t];
      acc[t][r] = v;
      sm[r] += v; sq[r] += v*v;
    }
  }
  #pragma unroll
  for (int mask = 1; mask < 16; mask <<= 1){
    #pragma unroll
    for (int r = 0; r < 4; ++r){ sm[r] += __shfl_xor(sm[r], mask); sq[r] += __shfl_xor(sq[r], mask); }
  }
  #pragma unroll
  for (int r = 0; r < 4; ++r){
    float mean = sm[r] * (1.0f/128.0f);
    float var  = sq[r]*(1.0f/128.0f) - mean*mean;
    float rstd = rsqrtf(var + 1e-5f);
    #pragma unroll
    for (int t = 0; t < 8; ++t){
      float y = (acc[t][r] - mean) * rstd * pg[t] + pe[t];
      y = y / (1.0f + __expf(-y));       // SiLU
      fw[(g*4 + r)*264 + t*16 + c16] = bfr(y);
    }
  }
}

__device__ __forceinline__ void geo_store(
    float rx, float ry, float rz,
    const float* s_cw1, const float* s_cb1, const float* s_sc, const float* s_sh,
    const short* __restrict__ cw2f, const float (&pc2)[8],
    short* fw, int g, int c16, int lane)
{
  bf16x8 a2[2];
  #pragma unroll
  for (int ks = 0; ks < 2; ++ks){
    bf16x8 v;
    #pragma unroll
    for (int j = 0; j < 8; ++j){
      int o = ks*32 + g*8 + j;
      float h = s_cw1[o*3]*rx + s_cw1[o*3+1]*ry + s_cw1[o*3+2]*rz + s_cb1[o];
      h = h * s_sc[o] + s_sh[o];
      h = h / (1.0f + __expf(-h));
      v[j] = bfr(h);
    }
    a2[ks] = v;
  }
  #pragma unroll
  for (int t = 0; t < 8; ++t){
    f32x4 a = (f32x4){0.f,0.f,0.f,0.f};
    #pragma unroll
    for (int ks = 0; ks < 2; ++ks){
      bf16x8 w = *(const bf16x8*)(cw2f + ((t*2 + ks)*64 + lane)*8);   // coalesced frag
      a = __builtin_amdgcn_mfma_f32_16x16x32_bf16(a2[ks], w, a, 0, 0, 0);
    }
    #pragma unroll
    for (int r = 0; r < 4; ++r)
      fw[(g*4 + r)*264 + 128 + t*16 + c16] = bfr(a[r] + pc2[t]);
  }
}

__device__ __forceinline__ void epilogue_store(
    f32x4 (&acc)[8], const float (&pbf)[8], const float (&pgf)[8], const float (&pef)[8],
    const float (&pal)[8], const float (&pbt)[8],
    int point, int g, int c16, float* __restrict__ out)
{
  float sm[4] = {0,0,0,0}, sq[4] = {0,0,0,0};
  #pragma unroll
  for (int t = 0; t < 8; ++t){
    #pragma unroll
    for (int r = 0; r < 4; ++r){
      float v = acc[t][r] + pbf[t];
      acc[t][r] = v;
      sm[r] += v; sq[r] += v*v;
    }
  }
  #pragma unroll
  for (int mask = 1; mask < 16; mask <<= 1){
    #pragma unroll
    for (int r = 0; r < 4; ++r){ sm[r] += __shfl_xor(sm[r], mask); sq[r] += __shfl_xor(sq[r], mask); }
  }
  #pragma unroll
  for (int r = 0; r < 4; ++r){
    float mean = sm[r] * (1.0f/128.0f);
    float var  = sq[r]*(1.0f/128.0f) - mean*mean;
    float rstd = rsqrtf(var + 1e-5f);
    #pragma unroll
    for (int t = 0; t < 8; ++t){
      float y = (acc[t][r] - mean) * rstd * pgf[t] + pef[t];
      y = y / (1.0f + __expf(-y));
      acc[t][r] = pal[t]*y + pbt[t];
    }
  }
  float sr[4] = {0,0,0,0};
  #pragma unroll
  for (int t = 0; t < 8; ++t){
    #pragma unroll
    for (int r = 0; r < 4; ++r) sr[r] += acc[t][r];
  }
  #pragma unroll
  for (int mask = 1; mask < 16; mask <<= 1){
    #pragma unroll
    for (int r = 0; r < 4; ++r) sr[r] += __shfl_xor(sr[r], mask);
  }
  float mx = fmaxf(fmaxf(sr[0], sr[1]), fmaxf(sr[2], sr[3]));
  mx = fmaxf(mx, __shfl_xor(mx, 16));
  mx = fmaxf(mx, __shfl_xor(mx, 32));
  float e[4]; float se = 0.f;
  #pragma unroll
  for (int r = 0; r < 4; ++r){ e[r] = __expf(sr[r] - mx); se += e[r]; }
  se += __shfl_xor(se, 16);
  se += __shfl_xor(se, 32);
  float inv = 1.0f / se;
  #pragma unroll
  for (int r = 0; r < 4; ++r) e[r] *= inv;
  #pragma unroll
  for (int t = 0; t < 8; ++t){
    float o = e[0]*acc[t][0] + e[1]*acc[t][1] + e[2]*acc[t][2] + e[3]*acc[t][3];
    o += __shfl_xor(o, 16);
    o += __shfl_xor(o, 32);
    if (g == 0) out[point*128 + t*16 + c16] = o;
  }
}

__global__ __launch_bounds__(256) void lga_main_kernel(
    const float* __restrict__ xyz, const float* __restrict__ feats, const int* __restrict__ idx_ws,
    const short* __restrict__ W1Tf, const short* __restrict__ WfTf, const short* __restrict__ cw2f,
    const float* __restrict__ b1, const float* __restrict__ ln1g, const float* __restrict__ ln1b,
    const float* __restrict__ cw1, const float* __restrict__ cb1,
    const float* __restrict__ bnsc, const float* __restrict__ bnsh,
    const float* __restrict__ cb2, const float* __restrict__ bfb,
    const float* __restrict__ lnfg, const float* __restrict__ lnfb,
    const float* __restrict__ alpha, const float* __restrict__ beta,
    float* __restrict__ out)
{
  __shared__ short fuse[4][16][264];     // per-wave private concat buffer
  __shared__ float s_cw1[192], s_cb1[64], s_sc[64], s_sh[64];

  int tid = threadIdx.x;
  for (int i = tid; i < 192; i += 256) s_cw1[i] = cw1[i];
  if (tid < 64){ s_cb1[tid] = cb1[tid]; s_sc[tid] = bnsc[tid]; s_sh[tid] = bnsh[tid]; }
  __syncthreads();                       // cross-wave staging barrier (kept)

  int wv = tid >> 6, lane = tid & 63, g = lane >> 4, c16 = lane & 15;
  int point = blockIdx.x*4 + wv;
  int bb = point >> 12, n = point & 4095;

  int nb = idx_ws[point*16 + c16];
  const float* frow = feats + (bb*N_ + nb)*128;
  bf16x8 a1[4];
  #pragma unroll
  for (int ks = 0; ks < 4; ++ks){
    f32x4 lo = *(const f32x4*)(frow + ks*32 + g*8);
    f32x4 hi = *(const f32x4*)(frow + ks*32 + g*8 + 4);
    bf16x8 v;
    v[0]=bfr(lo[0]); v[1]=bfr(lo[1]); v[2]=bfr(lo[2]); v[3]=bfr(lo[3]);
    v[4]=bfr(hi[0]); v[5]=bfr(hi[1]); v[6]=bfr(hi[2]); v[7]=bfr(hi[3]);
    a1[ks] = v;
  }

  // GEMM1, fragment-ordered (coalesced) B loads
  f32x4 acc[8];
  #pragma unroll
  for (int t = 0; t < 8; ++t) acc[t] = (f32x4){0.f,0.f,0.f,0.f};
  #pragma unroll
  for (int t = 0; t < 8; ++t){
    #pragma unroll
    for (int ks = 0; ks < 4; ++ks){
      bf16x8 w = *(const bf16x8*)(W1Tf + ((t*4 + ks)*64 + lane)*8);
      acc[t] = __builtin_amdgcn_mfma_f32_16x16x32_bf16(a1[ks], w, acc[t], 0, 0, 0);
    }
  }

  short* fw = &fuse[wv][0][0];
  {
    float p_b1[8], p_g1[8], p_e1[8];
    #pragma unroll
    for (int t = 0; t < 8; ++t){
      int col = t*16 + c16;
      p_b1[t] = b1[col]; p_g1[t] = ln1g[col]; p_e1[t] = ln1b[col];
    }
    ln_silu_store(acc, p_b1, p_g1, p_e1, fw, g, c16);
  }
  {
    float p_c2[8];
    #pragma unroll
    for (int t = 0; t < 8; ++t) p_c2[t] = cb2[t*16 + c16];
    const float* cx = xyz + (bb*N_ + n)*3;
    const float* nx = xyz + (bb*N_ + nb)*3;
    geo_store(nx[0]-cx[0], nx[1]-cx[1], nx[2]-cx[2],
              s_cw1, s_cb1, s_sc, s_sh, cw2f, p_c2, fw, g, c16, lane);
  }

  // read a3 (same-wave LDS RAW; DS-pipe ordered, no barrier needed)
  bf16x8 a3[8];
  #pragma unroll
  for (int ks = 0; ks < 8; ++ks)
    a3[ks] = *(const bf16x8*)(fw + c16*264 + ks*32 + g*8);

  // GEMM3, fragment-ordered (coalesced) B loads, streamed
  #pragma unroll
  for (int t = 0; t < 8; ++t) acc[t] = (f32x4){0.f,0.f,0.f,0.f};
  #pragma unroll
  for (int t = 0; t < 8; ++t){
    #pragma unroll
    for (int ks = 0; ks < 8; ++ks){
      bf16x8 w = *(const bf16x8*)(WfTf + ((t*8 + ks)*64 + lane)*8);
      acc[t] = __builtin_amdgcn_mfma_f32_16x16x32_bf16(a3[ks], w, acc[t], 0, 0, 0);
    }
  }

  // epilogue params loaded late to cap register pressure
  float p_bf[8], p_gf[8], p_ef[8], p_al[8], p_bt[8];
  #pragma unroll
  for (int t = 0; t < 8; ++t){
    int col = t*16 + c16;
    p_bf[t] = bfb[col]; p_gf[t] = lnfg[col]; p_ef[t] = lnfb[col];
    p_al[t] = alpha[col]; p_bt[t] = beta[col];
  }
  epilogue_store(acc, p_bf, p_gf, p_ef, p_al, p_bt, point, g, c16, out);
}

// ---------------- launch ----------------
extern "C" void kernel_launch(void* const* d_in, const int* in_sizes, int n_in,
                              void* d_out, int out_size, void* d_ws, size_t ws_size,
                              hipStream_t stream)
{
  (void)in_sizes; (void)n_in; (void)out_size; (void)ws_size;
  const float* xyz   = (const float*)d_in[0];
  const float* feats = (const float*)d_in[1];
  const float* W1    = (const float*)d_in[2];
  const float* b1    = (const float*)d_in[3];
  const float* ln1g  = (const float*)d_in[4];
  const float* ln1b  = (const float*)d_in[5];
  const float* cw1   = (const float*)d_in[6];
  const float* cb1   = (const float*)d_in[7];
  const float* bng   = (const float*)d_in[8];
  const float* bnb   = (const float*)d_in[9];
  const float* cw2   = (const float*)d_in[10];
  const float* cb2   = (const float*)d_in[11];
  const float* Wf    = (const float*)d_in[12];
  const float* bfb   = (const float*)d_in[13];
  const float* lnfg  = (const float*)d_in[14];
  const float* lnfb  = (const float*)d_in[15];
  const float* alpha = (const float*)d_in[16];
  const float* beta  = (const float*)d_in[17];

  char* ws = (char*)d_ws;
  int*   idx   = (int*)  (ws);                 // 2,097,152 B
  float* stats = (float*)(ws + 2097152);       // 16 floats
  float* bnsc  = (float*)(ws + 2097216);       // 64 floats
  float* bnsh  = (float*)(ws + 2097472);       // 64 floats
  short* W1Tf  = (short*)(ws + 2097728);       // 32 KB (fragment order)
  short* WfTf  = (short*)(ws + 2130496);       // 64 KB (fragment order)
  short* cw2f  = (short*)(ws + 2196032);       // 16 KB (fragment order)

  // partial KNN lists live in d_out (dead storage until lga_main fully
  // overwrites it): 4 quarters x 32768 q x 16 = 8 MB d + 8 MB idx = 16 MB.
  float* pdb = (float*)d_out;
  int*   pib = (int*)((char*)d_out + 8388608);

  hipLaunchKernelGGL(prep_kernel, dim3(225), dim3(256), 0, stream,
                     W1, Wf, cw2, W1Tf, WfTf, cw2f, stats);
  hipLaunchKernelGGL(knn_split_kernel, dim3(2048), dim3(512), 0, stream,
                     xyz, pdb, pib);
  hipLaunchKernelGGL(knn_merge_kernel, dim3(64), dim3(512), 0, stream,
                     xyz, pdb, pib, idx, stats);
  hipLaunchKernelGGL(bn_finalize_kernel, dim3(1), dim3(64), 0, stream,
                     stats, cw1, cb1, bng, bnb, bnsc, bnsh);
  hipLaunchKernelGGL(lga_main_kernel, dim3(8192), dim3(256), 0, stream,
                     xyz, feats, idx, W1Tf, WfTf, cw2f,
                     b1, ln1g, ln1b, cw1, cb1, bnsc, bnsh,
                     cb2, bfb, lnfg, lnfb, alpha, beta,
                     (float*)d_out);
}

// Round 20
// 960.591 us; speedup vs baseline: 1.1639x; 1.1639x over previous
//
#include <hip/hip_runtime.h>
#include <hip/hip_bf16.h>

#define B_ 8
#define N_ 4096
#define K_ 16
#define D_ 128

typedef short bf16x8 __attribute__((ext_vector_type(8)));
typedef float f32x4 __attribute__((ext_vector_type(4)));

__device__ __forceinline__ short bfr(float x){
  __hip_bfloat16 h = __float2bfloat16(x);
  return *reinterpret_cast<short*>(&h);
}

// ---------------- prep: weights in MFMA-FRAGMENT ORDER + zero stats ---------
__global__ __launch_bounds__(256) void prep_kernel(
    const float* __restrict__ W1, const float* __restrict__ Wf, const float* __restrict__ cw2,
    short* __restrict__ W1Tf, short* __restrict__ WfTf, short* __restrict__ cw2f,
    float* __restrict__ stats)
{
  int t = blockIdx.x*256 + threadIdx.x;
  if (t < 16384) {                       // W1 frags: t(8) x ks(4) x lane x j
    int u = t;
    int j = u & 7, L = (u >> 3) & 63, ks = (u >> 9) & 3, tt = u >> 11;
    int d = tt*16 + (L & 15);
    int c = ks*32 + (L >> 4)*8 + j;
    W1Tf[u] = bfr(W1[c*128 + d]);        // W1 is [CIN=128][D=128]
  } else if (t < 49152) {                // Wf frags: t(8) x ks(8) x lane x j
    int u = t - 16384;
    int j = u & 7, L = (u >> 3) & 63, ks = (u >> 9) & 7, tt = u >> 12;
    int d = tt*16 + (L & 15);
    int c = ks*32 + (L >> 4)*8 + j;
    WfTf[u] = bfr(Wf[c*128 + d]);        // Wf is [2D=256][D=128]
  } else if (t < 57344) {                // cw2 frags: t(8) x ks(2) x lane x j
    int u = t - 49152;
    int j = u & 7, L = (u >> 3) & 63, ks = (u >> 9) & 1, tt = u >> 10;
    int d = tt*16 + (L & 15);
    int c = ks*32 + (L >> 4)*8 + j;
    cw2f[u] = bfr(cw2[d*64 + c]);        // cw2 is [D=128][D/2=64]
  } else if (t < 57360) {
    stats[t - 57344] = 0.0f;
  }
}

// ---------------- knn: split scan, no prefetch (R18-proven optimum) ---------
__device__ __forceinline__ void insert16(float (&bd)[16], int (&bi)[16], float d, int cid){
  #pragma unroll
  for (int j = 15; j >= 1; --j){
    bool ltj = d < bd[j];
    bool ltp = d < bd[j-1];
    float nd = ltj ? (ltp ? bd[j-1] : d) : bd[j];
    int   ni = ltj ? (ltp ? bi[j-1] : cid) : bi[j];
    bd[j] = nd; bi[j] = ni;
  }
  bool lt0 = d < bd[0];
  bd[0] = lt0 ? d : bd[0];
  bi[0] = lt0 ? cid : bi[0];
}

__device__ __forceinline__ void insert16t(float (&bd)[16], int (&bi)[16], float d, int cid){
  bool lt[16];
  #pragma unroll
  for (int j = 0; j < 16; ++j)
    lt[j] = (d < bd[j]) || ((d == bd[j]) && (cid < bi[j]));
  #pragma unroll
  for (int j = 15; j >= 1; --j){
    float nd = lt[j] ? (lt[j-1] ? bd[j-1] : d) : bd[j];
    int   ni = lt[j] ? (lt[j-1] ? bi[j-1] : cid) : bi[j];
    bd[j] = nd; bi[j] = ni;
  }
  if (lt[0]){ bd[0] = d; bi[0] = cid; }
}

__global__ __launch_bounds__(512) void knn_split_kernel(
    const float* __restrict__ xyz,
    float* __restrict__ pd0, int* __restrict__ pi0,
    float* __restrict__ pd1, int* __restrict__ pi1)
{
  __shared__ float4 cand[2048];          // 32 KB: x,y,z,|p|^2 (XOR-swizzled)
  int b    = blockIdx.x >> 7;            // batch
  int h    = (blockIdx.x >> 6) & 1;      // candidate half
  int qblk = (blockIdx.x & 63) << 6;     // 64 queries per block
  int hbase = h << 11;                   // 2048*h
  const float* xb = xyz + b*N_*3;
  for (int i = threadIdx.x; i < 2048; i += 512){
    int gi = hbase + i;
    float x = xb[gi*3+0], y = xb[gi*3+1], z = xb[gi*3+2];
    int e = i ^ ((i >> 8) & 7);          // swizzled slot (bijection within slice)
    cand[e] = make_float4(x, y, z, x*x + y*y + z*z);
  }
  __syncthreads();

  int wv = threadIdx.x >> 6, lane = threadIdx.x & 63;
  int q = lane & 7;                      // query within wave's 8
  int s = lane >> 3;                     // slice 0..7 (256 cands each)
  int qi = qblk + (wv << 3) + q;         // batch-local query index
  const float* qp = xb + qi*3;
  float qx = qp[0], qy = qp[1], qz = qp[2];
  float4 qc = make_float4(qx, qy, qz, qx*qx + qy*qy + qz*qz);

  float bd[16]; int bi[16];
  #pragma unroll
  for (int j = 0; j < 16; ++j){ bd[j] = 3.4e38f; bi[j] = 0x7fffffff; }

  // ascending-index scan of slice [s*256, (s+1)*256) — simple body
  int cbase = s << 8;
  for (int m = 0; m < 256; ++m){
    float4 c = cand[cbase + (m ^ s)];
    float t = qc.x*c.x + qc.y*c.y + qc.z*c.z;
    float d = (qc.w + c.w) - 2.0f*t;
    if (d < bd[15]) insert16(bd, bi, d, cbase + m);
  }

  // lex-aware absorb-tree merge over slice bits (order-independent)
  #pragma unroll
  for (int xm = 32; xm >= 8; xm >>= 1){
    bool absorb = (lane & xm) == 0;
    #pragma unroll
    for (int j = 0; j < 16; ++j){
      float pdj = __shfl_xor(bd[j], xm);
      int   pij = __shfl_xor(bi[j], xm);
      if (absorb) insert16t(bd, bi, pdj, pij);
    }
  }

  // lanes with s==0 write this half's exact lex-sorted partial list
  if (s == 0){
    int gq = b*N_ + qi;
    float* pdh = h ? pd1 : pd0;
    int*   pih = h ? pi1 : pi0;
    #pragma unroll
    for (int j = 0; j < 16; ++j){
      pdh[gq*16 + j] = bd[j];
      pih[gq*16 + j] = bi[j] + hbase;    // translate to global candidate index
    }
  }
}

// lex compare on stored scan bits (no recompute -> no drift)
__device__ __forceinline__ bool lexlt(float da, int ia, float db, int ib){
  return (da < db) || ((da == db) && (ia < ib));
}

__global__ __launch_bounds__(512) void knn_merge_kernel(
    const float* __restrict__ xyz,
    const float* __restrict__ pd0, const int* __restrict__ pi0,
    const float* __restrict__ pd1, const int* __restrict__ pi1,
    int* __restrict__ idx_out, float* __restrict__ stats)
{
  int gq = blockIdx.x*512 + threadIdx.x;   // 64 blocks x 512 = 32768 queries
  int b = gq >> 12, qi = gq & 4095;

  float md[16]; int mi[16];
  #pragma unroll
  for (int i = 0; i < 16; ++i){
    float da = pd0[gq*16 + i];      int ia = pi0[gq*16 + i];
    float db = pd1[gq*16 + 15 - i]; int ib = pi1[gq*16 + 15 - i];
    bool t = lexlt(da, ia, db, ib);
    md[i] = t ? da : db; mi[i] = t ? ia : ib;
  }
  #pragma unroll
  for (int j = 8; j > 0; j >>= 1){
    #pragma unroll
    for (int i = 0; i < 16; ++i){
      int l = i ^ j;
      if (l > i){
        bool t = lexlt(md[l], mi[l], md[i], mi[i]);   // true -> swap
        float lo_d = t ? md[l] : md[i]; int lo_i = t ? mi[l] : mi[i];
        float hi_d = t ? md[i] : md[l]; int hi_i = t ? mi[i] : mi[l];
        md[i] = lo_d; mi[i] = lo_i; md[l] = hi_d; mi[l] = hi_i;
      }
    }
  }

  const float* qp = xyz + (b*N_ + qi)*3;
  float qx = qp[0], qy = qp[1], qz = qp[2];
  float sv[9];
  #pragma unroll
  for (int i = 0; i < 9; ++i) sv[i] = 0.0f;
  #pragma unroll
  for (int j = 0; j < 16; ++j){
    idx_out[gq*16 + j] = mi[j];
    const float* np = xyz + (b*N_ + mi[j])*3;
    float rx = np[0]-qx, ry = np[1]-qy, rz = np[2]-qz;
    sv[0] += rx;    sv[1] += ry;    sv[2] += rz;
    sv[3] += rx*rx; sv[4] += ry*ry; sv[5] += rz*rz;
    sv[6] += rx*ry; sv[7] += rx*rz; sv[8] += ry*rz;
  }
  #pragma unroll
  for (int i = 0; i < 9; ++i){
    float v = sv[i];
    #pragma unroll
    for (int mask = 1; mask < 64; mask <<= 1) v += __shfl_xor(v, mask);
    if ((threadIdx.x & 63) == 0) atomicAdd(&stats[i], v);
  }
}

// ---------------- BN finalize ----------------
__global__ void bn_finalize_kernel(
    const float* __restrict__ stats, const float* __restrict__ cw1, const float* __restrict__ cb1,
    const float* __restrict__ bn_g, const float* __restrict__ bn_b,
    float* __restrict__ bnsc, float* __restrict__ bnsh)
{
  int o = threadIdx.x;
  if (o >= 64) return;
  const float inv = 1.0f / (float)(B_*N_*K_);
  float m1x = stats[0]*inv, m1y = stats[1]*inv, m1z = stats[2]*inv;
  float mxx = stats[3]*inv, myy = stats[4]*inv, mzz = stats[5]*inv;
  float mxy = stats[6]*inv, mxz = stats[7]*inv, myz = stats[8]*inv;
  float w0 = cw1[o*3], w1 = cw1[o*3+1], w2 = cw1[o*3+2], cb = cb1[o];
  float wm = w0*m1x + w1*m1y + w2*m1z;
  float mu = wm + cb;
  float e2 = w0*w0*mxx + w1*w1*myy + w2*w2*mzz
           + 2.0f*(w0*w1*mxy + w0*w2*mxz + w1*w2*myz)
           + 2.0f*cb*wm + cb*cb;
  float var = e2 - mu*mu;
  float sc = bn_g[o] * rsqrtf(var + 1e-5f);
  bnsc[o] = sc;
  bnsh[o] = bn_b[o] - mu*sc;
}

// ---------------- main fused kernel: 1 wave = 1 point, low-VGPR -------------
__device__ __forceinline__ void ln_silu_store(
    f32x4 (&acc)[8], const float (&pb)[8], const float (&pg)[8], const float (&pe)[8],
    short* fw, int g, int c16)
{
  float sm[4] = {0,0,0,0}, sq[4] = {0,0,0,0};
  #pragma unroll
  for (int t = 0; t < 8; ++t){
    #pragma unroll
    for (int r = 0; r < 4; ++r){
      float v = acc[t][r] + pb[t];
      acc[t][r] = v;
      sm[r] += v; sq[r] += v*v;
    }
  }
  #pragma unroll
  for (int mask = 1; mask < 16; mask <<= 1){
    #pragma unroll
    for (int r = 0; r < 4; ++r){ sm[r] += __shfl_xor(sm[r], mask); sq[r] += __shfl_xor(sq[r], mask); }
  }
  #pragma unroll
  for (int r = 0; r < 4; ++r){
    float mean = sm[r] * (1.0f/128.0f);
    float var  = sq[r]*(1.0f/128.0f) - mean*mean;
    float rstd = rsqrtf(var + 1e-5f);
    #pragma unroll
    for (int t = 0; t < 8; ++t){
      float y = (acc[t][r] - mean) * rstd * pg[t] + pe[t];
      y = y / (1.0f + __expf(-y));       // SiLU
      fw[(g*4 + r)*264 + t*16 + c16] = bfr(y);
    }
  }
}

__device__ __forceinline__ void geo_store(
    float rx, float ry, float rz,
    const float* s_cw1, const float* s_cb1, const float* s_sc, const float* s_sh,
    const short* __restrict__ cw2f, const float (&pc2)[8],
    short* fw, int g, int c16, int lane)
{
  bf16x8 a2[2];
  #pragma unroll
  for (int ks = 0; ks < 2; ++ks){
    bf16x8 v;
    #pragma unroll
    for (int j = 0; j < 8; ++j){
      int o = ks*32 + g*8 + j;
      float h = s_cw1[o*3]*rx + s_cw1[o*3+1]*ry + s_cw1[o*3+2]*rz + s_cb1[o];
      h = h * s_sc[o] + s_sh[o];
      h = h / (1.0f + __expf(-h));
      v[j] = bfr(h);
    }
    a2[ks] = v;
  }
  #pragma unroll
  for (int t = 0; t < 8; ++t){
    f32x4 a = (f32x4){0.f,0.f,0.f,0.f};
    #pragma unroll
    for (int ks = 0; ks < 2; ++ks){
      bf16x8 w = *(const bf16x8*)(cw2f + ((t*2 + ks)*64 + lane)*8);   // coalesced frag
      a = __builtin_amdgcn_mfma_f32_16x16x32_bf16(a2[ks], w, a, 0, 0, 0);
    }
    #pragma unroll
    for (int r = 0; r < 4; ++r)
      fw[(g*4 + r)*264 + 128 + t*16 + c16] = bfr(a[r] + pc2[t]);
  }
}

__device__ __forceinline__ void epilogue_store(
    f32x4 (&acc)[8], const float (&pbf)[8], const float (&pgf)[8], const float (&pef)[8],
    const float (&pal)[8], const float (&pbt)[8],
    int point, int g, int c16, float* __restrict__ out)
{
  float sm[4] = {0,0,0,0}, sq[4] = {0,0,0,0};
  #pragma unroll
  for (int t = 0; t < 8; ++t){
    #pragma unroll
    for (int r = 0; r < 4; ++r){
      float v = acc[t][r] + pbf[t];
      acc[t][r] = v;
      sm[r] += v; sq[r] += v*v;
    }
  }
  #pragma unroll
  for (int mask = 1; mask < 16; mask <<= 1){
    #pragma unroll
    for (int r = 0; r < 4; ++r){ sm[r] += __shfl_xor(sm[r], mask); sq[r] += __shfl_xor(sq[r], mask); }
  }
  #pragma unroll
  for (int r = 0; r < 4; ++r){
    float mean = sm[r] * (1.0f/128.0f);
    float var  = sq[r]*(1.0f/128.0f) - mean*mean;
    float rstd = rsqrtf(var + 1e-5f);
    #pragma unroll
    for (int t = 0; t < 8; ++t){
      float y = (acc[t][r] - mean) * rstd * pgf[t] + pef[t];
      y = y / (1.0f + __expf(-y));
      acc[t][r] = pal[t]*y + pbt[t];
    }
  }
  float sr[4] = {0,0,0,0};
  #pragma unroll
  for (int t = 0; t < 8; ++t){
    #pragma unroll
    for (int r = 0; r < 4; ++r) sr[r] += acc[t][r];
  }
  #pragma unroll
  for (int mask = 1; mask < 16; mask <<= 1){
    #pragma unroll
    for (int r = 0; r < 4; ++r) sr[r] += __shfl_xor(sr[r], mask);
  }
  float mx = fmaxf(fmaxf(sr[0], sr[1]), fmaxf(sr[2], sr[3]));
  mx = fmaxf(mx, __shfl_xor(mx, 16));
  mx = fmaxf(mx, __shfl_xor(mx, 32));
  float e[4]; float se = 0.f;
  #pragma unroll
  for (int r = 0; r < 4; ++r){ e[r] = __expf(sr[r] - mx); se += e[r]; }
  se += __shfl_xor(se, 16);
  se += __shfl_xor(se, 32);
  float inv = 1.0f / se;
  #pragma unroll
  for (int r = 0; r < 4; ++r) e[r] *= inv;
  #pragma unroll
  for (int t = 0; t < 8; ++t){
    float o = e[0]*acc[t][0] + e[1]*acc[t][1] + e[2]*acc[t][2] + e[3]*acc[t][3];
    o += __shfl_xor(o, 16);
    o += __shfl_xor(o, 32);
    if (g == 0) out[point*128 + t*16 + c16] = o;
  }
}

__global__ __launch_bounds__(256) void lga_main_kernel(
    const float* __restrict__ xyz, const float* __restrict__ feats, const int* __restrict__ idx_ws,
    const short* __restrict__ W1Tf, const short* __restrict__ WfTf, const short* __restrict__ cw2f,
    const float* __restrict__ b1, const float* __restrict__ ln1g, const float* __restrict__ ln1b,
    const float* __restrict__ cw1, const float* __restrict__ cb1,
    const float* __restrict__ bnsc, const float* __restrict__ bnsh,
    const float* __restrict__ cb2, const float* __restrict__ bfb,
    const float* __restrict__ lnfg, const float* __restrict__ lnfb,
    const float* __restrict__ alpha, const float* __restrict__ beta,
    float* __restrict__ out)
{
  __shared__ short fuse[4][16][264];     // per-wave private concat buffer
  __shared__ float s_cw1[192], s_cb1[64], s_sc[64], s_sh[64];

  int tid = threadIdx.x;
  for (int i = tid; i < 192; i += 256) s_cw1[i] = cw1[i];
  if (tid < 64){ s_cb1[tid] = cb1[tid]; s_sc[tid] = bnsc[tid]; s_sh[tid] = bnsh[tid]; }
  __syncthreads();                       // cross-wave staging barrier (kept)

  int wv = tid >> 6, lane = tid & 63, g = lane >> 4, c16 = lane & 15;
  int point = blockIdx.x*4 + wv;
  int bb = point >> 12, n = point & 4095;

  int nb = idx_ws[point*16 + c16];
  const float* frow = feats + (bb*N_ + nb)*128;
  bf16x8 a1[4];
  #pragma unroll
  for (int ks = 0; ks < 4; ++ks){
    f32x4 lo = *(const f32x4*)(frow + ks*32 + g*8);
    f32x4 hi = *(const f32x4*)(frow + ks*32 + g*8 + 4);
    bf16x8 v;
    v[0]=bfr(lo[0]); v[1]=bfr(lo[1]); v[2]=bfr(lo[2]); v[3]=bfr(lo[3]);
    v[4]=bfr(hi[0]); v[5]=bfr(hi[1]); v[6]=bfr(hi[2]); v[7]=bfr(hi[3]);
    a1[ks] = v;
  }

  // GEMM1, fragment-ordered (coalesced) B loads
  f32x4 acc[8];
  #pragma unroll
  for (int t = 0; t < 8; ++t) acc[t] = (f32x4){0.f,0.f,0.f,0.f};
  #pragma unroll
  for (int t = 0; t < 8; ++t){
    #pragma unroll
    for (int ks = 0; ks < 4; ++ks){
      bf16x8 w = *(const bf16x8*)(W1Tf + ((t*4 + ks)*64 + lane)*8);
      acc[t] = __builtin_amdgcn_mfma_f32_16x16x32_bf16(a1[ks], w, acc[t], 0, 0, 0);
    }
  }

  short* fw = &fuse[wv][0][0];
  {
    float p_b1[8], p_g1[8], p_e1[8];
    #pragma unroll
    for (int t = 0; t < 8; ++t){
      int col = t*16 + c16;
      p_b1[t] = b1[col]; p_g1[t] = ln1g[col]; p_e1[t] = ln1b[col];
    }
    ln_silu_store(acc, p_b1, p_g1, p_e1, fw, g, c16);
  }
  {
    float p_c2[8];
    #pragma unroll
    for (int t = 0; t < 8; ++t) p_c2[t] = cb2[t*16 + c16];
    const float* cx = xyz + (bb*N_ + n)*3;
    const float* nx = xyz + (bb*N_ + nb)*3;
    geo_store(nx[0]-cx[0], nx[1]-cx[1], nx[2]-cx[2],
              s_cw1, s_cb1, s_sc, s_sh, cw2f, p_c2, fw, g, c16, lane);
  }

  // read a3 (same-wave LDS RAW; DS-pipe ordered, no barrier needed)
  bf16x8 a3[8];
  #pragma unroll
  for (int ks = 0; ks < 8; ++ks)
    a3[ks] = *(const bf16x8*)(fw + c16*264 + ks*32 + g*8);

  // GEMM3, fragment-ordered (coalesced) B loads, streamed
  #pragma unroll
  for (int t = 0; t < 8; ++t) acc[t] = (f32x4){0.f,0.f,0.f,0.f};
  #pragma unroll
  for (int t = 0; t < 8; ++t){
    #pragma unroll
    for (int ks = 0; ks < 8; ++ks){
      bf16x8 w = *(const bf16x8*)(WfTf + ((t*8 + ks)*64 + lane)*8);
      acc[t] = __builtin_amdgcn_mfma_f32_16x16x32_bf16(a3[ks], w, acc[t], 0, 0, 0);
    }
  }

  // epilogue params loaded late to cap register pressure
  float p_bf[8], p_gf[8], p_ef[8], p_al[8], p_bt[8];
  #pragma unroll
  for (int t = 0; t < 8; ++t){
    int col = t*16 + c16;
    p_bf[t] = bfb[col]; p_gf[t] = lnfg[col]; p_ef[t] = lnfb[col];
    p_al[t] = alpha[col]; p_bt[t] = beta[col];
  }
  epilogue_store(acc, p_bf, p_gf, p_ef, p_al, p_bt, point, g, c16, out);
}

// ---------------- launch ----------------
extern "C" void kernel_launch(void* const* d_in, const int* in_sizes, int n_in,
                              void* d_out, int out_size, void* d_ws, size_t ws_size,
                              hipStream_t stream)
{
  (void)in_sizes; (void)n_in; (void)out_size; (void)ws_size;
  const float* xyz   = (const float*)d_in[0];
  const float* feats = (const float*)d_in[1];
  const float* W1    = (const float*)d_in[2];
  const float* b1    = (const float*)d_in[3];
  const float* ln1g  = (const float*)d_in[4];
  const float* ln1b  = (const float*)d_in[5];
  const float* cw1   = (const float*)d_in[6];
  const float* cb1   = (const float*)d_in[7];
  const float* bng   = (const float*)d_in[8];
  const float* bnb   = (const float*)d_in[9];
  const float* cw2   = (const float*)d_in[10];
  const float* cb2   = (const float*)d_in[11];
  const float* Wf    = (const float*)d_in[12];
  const float* bfb   = (const float*)d_in[13];
  const float* lnfg  = (const float*)d_in[14];
  const float* lnfb  = (const float*)d_in[15];
  const float* alpha = (const float*)d_in[16];
  const float* beta  = (const float*)d_in[17];

  char* ws = (char*)d_ws;
  int*   idx   = (int*)  (ws);                 // 2,097,152 B
  float* stats = (float*)(ws + 2097152);       // 16 floats
  float* bnsc  = (float*)(ws + 2097216);       // 64 floats
  float* bnsh  = (float*)(ws + 2097472);       // 64 floats
  short* W1Tf  = (short*)(ws + 2097728);       // 32 KB (fragment order)
  short* WfTf  = (short*)(ws + 2130496);       // 64 KB (fragment order)
  short* cw2f  = (short*)(ws + 2196032);       // 16 KB (fragment order)
  float* pd0   = (float*)(ws + 4194304);       // 2 MB (32768*16 f32)
  int*   pi0   = (int*)  (ws + 6291456);       // 2 MB
  float* pd1   = (float*)(ws + 8388608);       // 2 MB
  int*   pi1   = (int*)  (ws + 10485760);      // 2 MB

  hipLaunchKernelGGL(prep_kernel, dim3(225), dim3(256), 0, stream,
                     W1, Wf, cw2, W1Tf, WfTf, cw2f, stats);
  hipLaunchKernelGGL(knn_split_kernel, dim3(1024), dim3(512), 0, stream,
                     xyz, pd0, pi0, pd1, pi1);
  hipLaunchKernelGGL(knn_merge_kernel, dim3(64), dim3(512), 0, stream,
                     xyz, pd0, pi0, pd1, pi1, idx, stats);
  hipLaunchKernelGGL(bn_finalize_kernel, dim3(1), dim3(64), 0, stream,
                     stats, cw1, cb1, bng, bnb, bnsc, bnsh);
  hipLaunchKernelGGL(lga_main_kernel, dim3(8192), dim3(256), 0, stream,
                     xyz, feats, idx, W1Tf, WfTf, cw2f,
                     b1, ln1g, ln1b, cw1, cb1, bnsc, bnsh,
                     cb2, bfb, lnfg, lnfb, alpha, beta,
                     (float*)d_out);
}